// Round 2
// baseline (1528.558 us; speedup 1.0000x reference)
//
#include <hip/hip_runtime.h>
#include <math.h>

#define BB 64
#define SS 4096
#define DD 256
#define EE 32000
#define HH 5
#define EPSF 1e-12f

// ---------------- init: state = query ----------------
__global__ void k_init(const float* __restrict__ query, float* __restrict__ state) {
    int i = blockIdx.x * 256 + threadIdx.x;
    state[i] = query[i];
}

// ---------------- q = state @ Wq[h] + bq[h]; q_norm ----------------
__global__ void k_qproj(const float* __restrict__ state, const float* __restrict__ Wq,
                        const float* __restrict__ bq, float* __restrict__ qn, int h) {
    __shared__ float s_row[DD];
    __shared__ float red[4];
    int b = blockIdx.x, d = threadIdx.x;
    s_row[d] = state[b * DD + d];
    __syncthreads();
    const float* W = Wq + (size_t)h * DD * DD;
    float acc = bq[h * DD + d];
#pragma unroll 4
    for (int k = 0; k < DD; ++k) acc += s_row[k] * W[(size_t)k * DD + d];
    float ss = acc * acc;
    int lane = d & 63, wid = d >> 6;
#pragma unroll
    for (int off = 32; off; off >>= 1) ss += __shfl_down(ss, off);
    if (lane == 0) red[wid] = ss;
    __syncthreads();
    if (d == 0) red[0] = 1.0f / fmaxf(sqrtf(red[0] + red[1] + red[2] + red[3]), EPSF);
    __syncthreads();
    qn[b * DD + d] = acc * red[0];
}

// ---------------- logits[b,s] = dot(qn[b], keys[b,s]) * rnorm[b,s] ----------------
template <bool FIRST>
__global__ void k_qk(const float* __restrict__ keys, const float* __restrict__ qn,
                     float* __restrict__ rnorm, float* __restrict__ logits) {
    __shared__ float q[DD];
    int b = blockIdx.y;
    int s = blockIdx.x * 256 + threadIdx.x;
    q[threadIdx.x] = qn[b * DD + threadIdx.x];
    __syncthreads();
    const float4* kr = (const float4*)(keys + ((size_t)b * SS + s) * DD);
    float acc = 0.f, ss = 0.f;
#pragma unroll 8
    for (int i = 0; i < 64; ++i) {
        float4 kv = kr[i];
        acc += kv.x * q[4 * i] + kv.y * q[4 * i + 1] + kv.z * q[4 * i + 2] + kv.w * q[4 * i + 3];
        if (FIRST) ss += kv.x * kv.x + kv.y * kv.y + kv.z * kv.z + kv.w * kv.w;
    }
    float rn;
    if (FIRST) {
        rn = 1.0f / fmaxf(sqrtf(ss), EPSF);
        rnorm[(size_t)b * SS + s] = rn;
    } else {
        rn = rnorm[(size_t)b * SS + s];
    }
    logits[(size_t)b * SS + s] = acc * rn;
}

// ---------------- softmax over S per b; write attn ----------------
__global__ void k_softmax(const float* __restrict__ logits, float* __restrict__ attn_h) {
    __shared__ float red[4];
    int b = blockIdx.x, tid = threadIdx.x;
    const float* L = logits + (size_t)b * SS;
    float v[16];
    float m = -1e30f;
#pragma unroll
    for (int i = 0; i < 16; ++i) {
        v[i] = L[tid + i * 256];
        m = fmaxf(m, v[i]);
    }
    int lane = tid & 63, wid = tid >> 6;
#pragma unroll
    for (int off = 32; off; off >>= 1) m = fmaxf(m, __shfl_down(m, off));
    if (lane == 0) red[wid] = m;
    __syncthreads();
    m = fmaxf(fmaxf(red[0], red[1]), fmaxf(red[2], red[3]));
    __syncthreads();
    float sum = 0.f;
#pragma unroll
    for (int i = 0; i < 16; ++i) {
        v[i] = expf(v[i] - m);
        sum += v[i];
    }
#pragma unroll
    for (int off = 32; off; off >>= 1) sum += __shfl_down(sum, off);
    if (lane == 0) red[wid] = sum;
    __syncthreads();
    float inv = 1.0f / (red[0] + red[1] + red[2] + red[3]);
#pragma unroll
    for (int i = 0; i < 16; ++i) attn_h[(size_t)b * SS + tid + i * 256] = v[i] * inv;
}

// ---------------- partial PV: partials[c,b,d] = sum_{s in chunk} attn*values ----------------
__global__ void k_pv(const float* __restrict__ values, const float* __restrict__ attn_h,
                     float* __restrict__ partials) {
    __shared__ float a[512];
    int c = blockIdx.x, b = blockIdx.y, d = threadIdx.x;
    int s0 = c * 512;
    a[d] = attn_h[(size_t)b * SS + s0 + d];
    a[d + 256] = attn_h[(size_t)b * SS + s0 + 256 + d];
    __syncthreads();
    const float* V = values + ((size_t)b * SS + s0) * DD + d;
    float acc = 0.f;
#pragma unroll 4
    for (int s = 0; s < 512; ++s) acc += a[s] * V[(size_t)s * DD];
    partials[((size_t)c * BB + b) * DD + d] = acc;
}

// ---------------- state += sum of partials ----------------
__global__ void k_state(const float* __restrict__ partials, float* __restrict__ state) {
    int b = blockIdx.x, d = threadIdx.x;
    float acc = 0.f;
#pragma unroll
    for (int c = 0; c < 8; ++c) acc += partials[((size_t)c * BB + b) * DD + d];
    state[b * DD + d] += acc;
}

// ---------------- out_h[b,e] = state[b] @ Wd_h[:,e] + bd_h[e] ----------------
__global__ void k_outproj(const float* __restrict__ state, const float* __restrict__ Wd_h,
                          const float* __restrict__ bd_h, float* __restrict__ out_h) {
    __shared__ float st[BB * DD];  // 64 KB
    int tid = threadIdx.x;
    int e_local = tid & 63, quarter = tid >> 6;
    int e = blockIdx.x * 64 + e_local;
    for (int i = tid; i < BB * DD; i += 256) st[i] = state[i];
    __syncthreads();
    const float4* st4 = (const float4*)st;
    float acc[16];
#pragma unroll
    for (int i = 0; i < 16; ++i) acc[i] = 0.f;
    int bbase = quarter * 16;
    for (int k4 = 0; k4 < 64; ++k4) {
        float w0 = Wd_h[(size_t)(4 * k4 + 0) * EE + e];
        float w1 = Wd_h[(size_t)(4 * k4 + 1) * EE + e];
        float w2 = Wd_h[(size_t)(4 * k4 + 2) * EE + e];
        float w3 = Wd_h[(size_t)(4 * k4 + 3) * EE + e];
#pragma unroll
        for (int i = 0; i < 16; ++i) {
            float4 sv = st4[(size_t)(bbase + i) * 64 + k4];
            acc[i] += sv.x * w0 + sv.y * w1 + sv.z * w2 + sv.w * w3;
        }
    }
    float bde = bd_h[e];
#pragma unroll
    for (int i = 0; i < 16; ++i) {
        out_h[(size_t)(bbase + i) * EE + e] = acc[i] + bde;
    }
}

extern "C" void kernel_launch(void* const* d_in, const int* in_sizes, int n_in,
                              void* d_out, int out_size, void* d_ws, size_t ws_size,
                              hipStream_t stream) {
    const float* query  = (const float*)d_in[0];
    const float* keys   = (const float*)d_in[1];
    const float* values = (const float*)d_in[2];
    const float* Wq     = (const float*)d_in[3];
    const float* bq     = (const float*)d_in[4];
    const float* Wd     = (const float*)d_in[5];
    const float* bd     = (const float*)d_in[6];

    float* out = (float*)d_out;
    float* state      = out;                                        // [B,D]
    float* logits_out = out + (size_t)BB * DD;                      // [H,B,E]
    float* attn_out   = out + (size_t)BB * DD + (size_t)HH * BB * EE;  // [H,B,S]

    float* ws = (float*)d_ws;
    float* qn       = ws;                         // B*D
    float* rnorm    = qn + (size_t)BB * DD;       // B*S
    float* lg       = rnorm + (size_t)BB * SS;    // B*S
    float* partials = lg + (size_t)BB * SS;       // 8*B*D

    k_init<<<BB, 256, 0, stream>>>(query, state);

    for (int h = 0; h < HH; ++h) {
        k_qproj<<<BB, 256, 0, stream>>>(state, Wq, bq, qn, h);
        if (h == 0)
            k_qk<true><<<dim3(SS / 256, BB), 256, 0, stream>>>(keys, qn, rnorm, lg);
        else
            k_qk<false><<<dim3(SS / 256, BB), 256, 0, stream>>>(keys, qn, rnorm, lg);
        float* attn_h = attn_out + (size_t)h * BB * SS;
        k_softmax<<<BB, 256, 0, stream>>>(lg, attn_h);
        k_pv<<<dim3(8, BB), 256, 0, stream>>>(values, attn_h, partials);
        k_state<<<BB, 256, 0, stream>>>(partials, state);
        k_outproj<<<EE / 64, 256, 0, stream>>>(state, Wd + (size_t)h * DD * EE,
                                               bd + (size_t)h * EE,
                                               logits_out + (size_t)h * BB * EE);
    }
}